// Round 1
// baseline (648.501 us; speedup 1.0000x reference)
//
#include <hip/hip_runtime.h>
#include <math.h>

// Problem constants (from reference)
#define N_ENT 100000
#define N_REL 237
#define DIM   128
#define NE    400000
#define NCOPY 64   // rel-partial replication factor (XCD-aligned: copy%8 == blockIdx%8)

// ---------------------------------------------------------------------------
// Workspace layout (floats):
//  WaT      [384*128]            transposed Wa for coalesced GEMM reads
//  Ps       [N_ENT*128]          ent @ Wa[:,0:128]^T
//  Pd       [N_ENT*128]          ent @ Wa[:,256:384]^T
//  Pr       [N_REL*128]          rel @ Wa[:,128:256]^T + ba   (ba folded here)
//  ebsum    [N_ENT]
//  relp     [NCOPY*N_REL*128]    replicated rel partial sums
//  relcnt   [NCOPY*N_REL]        replicated rel counts
// total ~27.74M floats ~= 111 MB
// ---------------------------------------------------------------------------

__global__ void k_transpose_wa(const float* __restrict__ Wa, float* __restrict__ WaT) {
    int i = blockIdx.x * 256 + threadIdx.x;
    if (i < 384 * 128) {
        int k = i >> 7, j = i & 127;
        WaT[i] = Wa[j * 384 + k];   // WaT[k][j] = Wa[j][k]
    }
}

__global__ void k_proj_rel(const float* __restrict__ rel_e, const float* __restrict__ Wa,
                           const float* __restrict__ ba, float* __restrict__ Pr) {
    int i = blockIdx.x * 256 + threadIdx.x;
    if (i >= N_REL * DIM) return;
    int r = i >> 7, j = i & 127;
    float acc = ba[j];
    const float* wrow = Wa + j * 384 + 128;   // middle segment
    const float* erow = rel_e + r * DIM;
    #pragma unroll 8
    for (int k = 0; k < DIM; ++k) acc += erow[k] * wrow[k];
    Pr[i] = acc;
}

// Fused P_s / P_d projection: C[100000x128] twice, K=128, fp32 vector FMA.
// Block: 256 thr = 16 row-groups x 16 col-groups; thread computes 4 rows x 8 cols
// for BOTH output matrices (64 accum regs). ent tile staged in LDS (pad 132).
__global__ __launch_bounds__(256) void k_proj_ent(const float* __restrict__ ent,
        const float* __restrict__ WaT, float* __restrict__ Ps, float* __restrict__ Pd) {
    __shared__ float tile[64 * 132];
    const int tid = threadIdx.x;
    const int row0 = blockIdx.x * 64;

    // stage 64x128 ent rows (float4, coalesced)
    for (int i = tid; i < 64 * 32; i += 256) {
        int r = i >> 5, c4 = i & 31;
        float4 v = make_float4(0.f, 0.f, 0.f, 0.f);
        if (row0 + r < N_ENT) v = *(const float4*)(ent + (size_t)(row0 + r) * DIM + c4 * 4);
        *(float4*)(tile + r * 132 + c4 * 4) = v;
    }
    __syncthreads();

    const int rg = tid >> 4, cg = tid & 15;
    const int r0 = rg * 4, j0 = cg * 8;

    float accs[4][8], accd[4][8];
    #pragma unroll
    for (int i = 0; i < 4; ++i)
        #pragma unroll
        for (int j = 0; j < 8; ++j) { accs[i][j] = 0.f; accd[i][j] = 0.f; }

    for (int k = 0; k < DIM; k += 4) {
        #pragma unroll
        for (int kk = 0; kk < 4; ++kk) {
            float4 a0 = *(const float4*)(WaT + (k + kk) * 128 + j0);
            float4 a1 = *(const float4*)(WaT + (k + kk) * 128 + j0 + 4);
            float4 b0 = *(const float4*)(WaT + (256 + k + kk) * 128 + j0);
            float4 b1 = *(const float4*)(WaT + (256 + k + kk) * 128 + j0 + 4);
            float ws[8] = {a0.x, a0.y, a0.z, a0.w, a1.x, a1.y, a1.z, a1.w};
            float wd[8] = {b0.x, b0.y, b0.z, b0.w, b1.x, b1.y, b1.z, b1.w};
            #pragma unroll
            for (int i = 0; i < 4; ++i) {
                float e = tile[(r0 + i) * 132 + k + kk];
                #pragma unroll
                for (int j = 0; j < 8; ++j) {
                    accs[i][j] += e * ws[j];
                    accd[i][j] += e * wd[j];
                }
            }
        }
    }

    #pragma unroll
    for (int i = 0; i < 4; ++i) {
        int row = row0 + r0 + i;
        if (row < N_ENT) {
            float4 o;
            o = make_float4(accs[i][0], accs[i][1], accs[i][2], accs[i][3]);
            *(float4*)(Ps + (size_t)row * DIM + j0) = o;
            o = make_float4(accs[i][4], accs[i][5], accs[i][6], accs[i][7]);
            *(float4*)(Ps + (size_t)row * DIM + j0 + 4) = o;
            o = make_float4(accd[i][0], accd[i][1], accd[i][2], accd[i][3]);
            *(float4*)(Pd + (size_t)row * DIM + j0) = o;
            o = make_float4(accd[i][4], accd[i][5], accd[i][6], accd[i][7]);
            *(float4*)(Pd + (size_t)row * DIM + j0 + 4) = o;
        }
    }
}

// One wave per edge: c = Ps[src]+Pr[rel]+Pd[dst]; b = leaky(c.Wa2+ba2); eb=exp(b);
// atomics: hsum[src] += eb*c, ebsum[src] += eb, rel partials (replicated).
__global__ __launch_bounds__(256) void k_edge(const int* __restrict__ trip,
        const float* __restrict__ Ps, const float* __restrict__ Pd, const float* __restrict__ Pr,
        const float* __restrict__ Wa2, const float* __restrict__ ba2,
        float* __restrict__ hsum, float* __restrict__ ebsum,
        float* __restrict__ relp, float* __restrict__ relcnt) {
    const int lane = threadIdx.x & 63;
    const int wid  = (blockIdx.x * blockDim.x + threadIdx.x) >> 6;
    const int nw   = (gridDim.x * blockDim.x) >> 6;
    const int copy = blockIdx.x & (NCOPY - 1);
    const float w0 = Wa2[lane], w1 = Wa2[64 + lane];
    const float bb = ba2[0];

    for (int e = wid; e < NE; e += nw) {
        int s = trip[e * 3 + 0];
        int d = trip[e * 3 + 1];
        int r = trip[e * 3 + 2];
        float c0 = Ps[(size_t)s * DIM + lane]      + Pr[r * DIM + lane]      + Pd[(size_t)d * DIM + lane];
        float c1 = Ps[(size_t)s * DIM + 64 + lane] + Pr[r * DIM + 64 + lane] + Pd[(size_t)d * DIM + 64 + lane];
        float p = c0 * w0 + c1 * w1;
        #pragma unroll
        for (int off = 32; off > 0; off >>= 1) p += __shfl_xor(p, off, 64);
        float b = p + bb;
        b = (b > 0.f) ? b : 0.01f * b;        // leaky_relu, slope 0.01
        float eb = expf(b);
        float t0 = eb * c0, t1 = eb * c1;
        atomicAdd(hsum + (size_t)s * DIM + lane,      t0);
        atomicAdd(hsum + (size_t)s * DIM + 64 + lane, t1);
        atomicAdd(relp + (size_t)copy * (N_REL * DIM) + r * DIM + lane,      t0);
        atomicAdd(relp + (size_t)copy * (N_REL * DIM) + r * DIM + 64 + lane, t1);
        if (lane == 0) {
            atomicAdd(ebsum + s, eb);
            atomicAdd(relcnt + copy * N_REL + r, 1.0f);
        }
    }
}

__global__ void k_ent_final(float* __restrict__ out, const float* __restrict__ ebsum) {
    int i = blockIdx.x * 256 + threadIdx.x;
    if (i >= N_ENT * DIM) return;
    float s = ebsum[i >> 7];
    float ebs = (s == 0.f) ? 1e-12f : s;     // matches reference where()
    float x = out[i] / ebs;
    out[i] = (x > 0.f) ? x : expm1f(x);      // elu, alpha=1
}

__global__ void k_rel_final(float* __restrict__ out, const float* __restrict__ relp,
                            const float* __restrict__ relcnt) {
    int i = blockIdx.x * 256 + threadIdx.x;
    if (i >= N_REL * DIM) return;
    int r = i >> 7;
    float s = 0.f, c = 0.f;
    for (int cp = 0; cp < NCOPY; ++cp) {
        s += relp[(size_t)cp * (N_REL * DIM) + i];
        c += relcnt[cp * N_REL + r];
    }
    float h = s / fmaxf(c, 1.0f);
    out[N_ENT * DIM + i] = (h > 0.f) ? h : expm1f(h);
}

extern "C" void kernel_launch(void* const* d_in, const int* in_sizes, int n_in,
                              void* d_out, int out_size, void* d_ws, size_t ws_size,
                              hipStream_t stream) {
    const int*   trip = (const int*)d_in[0];
    const float* ent  = (const float*)d_in[1];
    const float* rele = (const float*)d_in[2];
    const float* Wa   = (const float*)d_in[3];
    const float* ba   = (const float*)d_in[4];
    const float* Wa2  = (const float*)d_in[5];
    const float* ba2  = (const float*)d_in[6];
    float* out = (float*)d_out;

    float* ws     = (float*)d_ws;
    float* WaT    = ws;                         // 384*128
    float* Ps     = WaT + 384 * 128;            // N_ENT*128
    float* Pd     = Ps + (size_t)N_ENT * DIM;   // N_ENT*128
    float* Pr     = Pd + (size_t)N_ENT * DIM;   // N_REL*128
    float* ebsum  = Pr + N_REL * DIM;           // N_ENT
    float* relp   = ebsum + N_ENT;              // NCOPY*N_REL*128
    float* relcnt = relp + (size_t)NCOPY * N_REL * DIM; // NCOPY*N_REL

    // zero accumulators (relp+relcnt are contiguous)
    hipMemsetAsync(ebsum, 0, N_ENT * sizeof(float), stream);
    hipMemsetAsync(relp, 0, ((size_t)NCOPY * N_REL * DIM + NCOPY * N_REL) * sizeof(float), stream);
    hipMemsetAsync(out, 0, (size_t)N_ENT * DIM * sizeof(float), stream);

    k_transpose_wa<<<192, 256, 0, stream>>>(Wa, WaT);
    k_proj_rel<<<(N_REL * DIM + 255) / 256, 256, 0, stream>>>(rele, Wa, ba, Pr);
    k_proj_ent<<<(N_ENT + 63) / 64, 256, 0, stream>>>(ent, WaT, Ps, Pd);
    k_edge<<<2048, 256, 0, stream>>>(trip, Ps, Pd, Pr, Wa2, ba2, out, ebsum, relp, relcnt);
    k_ent_final<<<(N_ENT * DIM + 255) / 256, 256, 0, stream>>>(out, ebsum);
    k_rel_final<<<(N_REL * DIM + 255) / 256, 256, 0, stream>>>(out, relp, relcnt);
}

// Round 2
// 513.833 us; speedup vs baseline: 1.2621x; 1.2621x over previous
//
#include <hip/hip_runtime.h>
#include <math.h>

// Problem constants (from reference)
#define N_ENT 100000
#define N_REL 237
#define DIM   128
#define NE    400000
#define NCOPY 64   // rel-partial replication factor

// ---------------------------------------------------------------------------
// Pipeline:
//  1. Per-node projections (6x fewer FLOPs than per-edge GEMM):
//     Ps = ent @ Wa[:,0:128]^T, Pd = ent @ Wa[:,256:384]^T, Pr = rel @ Wa[:,128:256]^T + ba
//  2. Build src-CSR on device: histogram -> hierarchical scan -> scatter (d,r) pairs.
//  3. k_seg: one wave per src entity. Register-accumulate sum(eb*c), sum(eb) over its
//     edges (no h_sum atomics!), finalize h_ent = ELU(acc/ebs) in-kernel, store once.
//     relp still via replicated fp32 atomics (205 MB write-through — next target).
//  4. rel histogram (LDS) + k_rel_final.
// ---------------------------------------------------------------------------
// Workspace layout (4B elems):
//  WaT[384*128] Ps[N_ENT*128] Pd[N_ENT*128] Pr[N_REL*128]
//  relp[NCOPY*N_REL*128] relcnt[N_REL]          (zeroed together)
//  row_start[N_ENT+1] cursor[N_ENT] bsum[128] sdst[NE] srel[NE]
//  total ~28.6M elems ~114.5 MB

__global__ void k_transpose_wa(const float* __restrict__ Wa, float* __restrict__ WaT) {
    int i = blockIdx.x * 256 + threadIdx.x;
    if (i < 384 * 128) {
        int k = i >> 7, j = i & 127;
        WaT[i] = Wa[j * 384 + k];   // WaT[k][j] = Wa[j][k]
    }
}

__global__ void k_proj_rel(const float* __restrict__ rel_e, const float* __restrict__ Wa,
                           const float* __restrict__ ba, float* __restrict__ Pr) {
    int i = blockIdx.x * 256 + threadIdx.x;
    if (i >= N_REL * DIM) return;
    int r = i >> 7, j = i & 127;
    float acc = ba[j];
    const float* wrow = Wa + j * 384 + 128;   // middle segment
    const float* erow = rel_e + r * DIM;
    #pragma unroll 8
    for (int k = 0; k < DIM; ++k) acc += erow[k] * wrow[k];
    Pr[i] = acc;
}

// Fused P_s / P_d projection (fp32 vector FMA, no fp32 MFMA on CDNA4).
__global__ __launch_bounds__(256) void k_proj_ent(const float* __restrict__ ent,
        const float* __restrict__ WaT, float* __restrict__ Ps, float* __restrict__ Pd) {
    __shared__ float tile[64 * 132];
    const int tid = threadIdx.x;
    const int row0 = blockIdx.x * 64;

    for (int i = tid; i < 64 * 32; i += 256) {
        int r = i >> 5, c4 = i & 31;
        float4 v = make_float4(0.f, 0.f, 0.f, 0.f);
        if (row0 + r < N_ENT) v = *(const float4*)(ent + (size_t)(row0 + r) * DIM + c4 * 4);
        *(float4*)(tile + r * 132 + c4 * 4) = v;
    }
    __syncthreads();

    const int rg = tid >> 4, cg = tid & 15;
    const int r0 = rg * 4, j0 = cg * 8;

    float accs[4][8], accd[4][8];
    #pragma unroll
    for (int i = 0; i < 4; ++i)
        #pragma unroll
        for (int j = 0; j < 8; ++j) { accs[i][j] = 0.f; accd[i][j] = 0.f; }

    for (int k = 0; k < DIM; k += 4) {
        #pragma unroll
        for (int kk = 0; kk < 4; ++kk) {
            float4 a0 = *(const float4*)(WaT + (k + kk) * 128 + j0);
            float4 a1 = *(const float4*)(WaT + (k + kk) * 128 + j0 + 4);
            float4 b0 = *(const float4*)(WaT + (256 + k + kk) * 128 + j0);
            float4 b1 = *(const float4*)(WaT + (256 + k + kk) * 128 + j0 + 4);
            float ws[8] = {a0.x, a0.y, a0.z, a0.w, a1.x, a1.y, a1.z, a1.w};
            float wd[8] = {b0.x, b0.y, b0.z, b0.w, b1.x, b1.y, b1.z, b1.w};
            #pragma unroll
            for (int i = 0; i < 4; ++i) {
                float e = tile[(r0 + i) * 132 + k + kk];
                #pragma unroll
                for (int j = 0; j < 8; ++j) {
                    accs[i][j] += e * ws[j];
                    accd[i][j] += e * wd[j];
                }
            }
        }
    }

    #pragma unroll
    for (int i = 0; i < 4; ++i) {
        int row = row0 + r0 + i;
        if (row < N_ENT) {
            float4 o;
            o = make_float4(accs[i][0], accs[i][1], accs[i][2], accs[i][3]);
            *(float4*)(Ps + (size_t)row * DIM + j0) = o;
            o = make_float4(accs[i][4], accs[i][5], accs[i][6], accs[i][7]);
            *(float4*)(Ps + (size_t)row * DIM + j0 + 4) = o;
            o = make_float4(accd[i][0], accd[i][1], accd[i][2], accd[i][3]);
            *(float4*)(Pd + (size_t)row * DIM + j0) = o;
            o = make_float4(accd[i][4], accd[i][5], accd[i][6], accd[i][7]);
            *(float4*)(Pd + (size_t)row * DIM + j0 + 4) = o;
        }
    }
}

// ---------------- CSR build ----------------
__global__ void k_hist(const int* __restrict__ trip, int* __restrict__ cnt) {
    int e = blockIdx.x * 256 + threadIdx.x;
    if (e < NE) atomicAdd(cnt + trip[3 * e], 1);
}

// 98 blocks x 256 thr; each thread owns 4 consecutive entries.
__global__ void k_scan1(const int* __restrict__ cnt, int* __restrict__ escan,
                        int* __restrict__ bsum) {
    __shared__ int sh[256];
    const int t = threadIdx.x;
    int base = blockIdx.x * 1024 + t * 4;
    int v[4]; int s = 0;
    #pragma unroll
    for (int k = 0; k < 4; ++k) { int idx = base + k; v[k] = (idx < N_ENT) ? cnt[idx] : 0; s += v[k]; }
    sh[t] = s; __syncthreads();
    for (int off = 1; off < 256; off <<= 1) {
        int u = (t >= off) ? sh[t - off] : 0;
        __syncthreads();
        sh[t] += u;
        __syncthreads();
    }
    int run = sh[t] - s;   // exclusive base for this thread
    #pragma unroll
    for (int k = 0; k < 4; ++k) { int idx = base + k; if (idx < N_ENT) escan[idx] = run; run += v[k]; }
    if (t == 255) bsum[blockIdx.x] = sh[255];
}

__global__ void k_scan2(int* __restrict__ bsum) {   // 1 block, 128 thr, in-place exclusive over 98
    __shared__ int sh[128];
    const int t = threadIdx.x;
    int v = (t < 98) ? bsum[t] : 0;
    sh[t] = v; __syncthreads();
    for (int off = 1; off < 128; off <<= 1) {
        int u = (t >= off) ? sh[t - off] : 0;
        __syncthreads();
        sh[t] += u;
        __syncthreads();
    }
    if (t < 98) bsum[t] = sh[t] - v;
}

__global__ void k_scan3(int* __restrict__ row_start, const int* __restrict__ bsum,
                        int* __restrict__ cursor) {
    int i = blockIdx.x * 256 + threadIdx.x;
    if (i < N_ENT) {
        int v = row_start[i] + bsum[i >> 10];
        row_start[i] = v;
        cursor[i] = v;
    } else if (i == N_ENT) {
        row_start[N_ENT] = NE;
    }
}

__global__ void k_scatter(const int* __restrict__ trip, int* __restrict__ cursor,
                          int* __restrict__ sdst, int* __restrict__ srel) {
    int e = blockIdx.x * 256 + threadIdx.x;
    if (e >= NE) return;
    int s = trip[3 * e], d = trip[3 * e + 1], r = trip[3 * e + 2];
    int pos = atomicAdd(cursor + s, 1);
    sdst[pos] = d;
    srel[pos] = r;
}

// rel counts = histogram of rel (LDS-aggregated, float output)
__global__ void k_rel_hist(const int* __restrict__ trip, float* __restrict__ relcnt) {
    __shared__ int lh[N_REL];
    for (int i = threadIdx.x; i < N_REL; i += 256) lh[i] = 0;
    __syncthreads();
    int e = blockIdx.x * 256 + threadIdx.x;
    if (e < NE) atomicAdd(&lh[trip[3 * e + 2]], 1);
    __syncthreads();
    for (int i = threadIdx.x; i < N_REL; i += 256)
        if (lh[i]) atomicAdd(relcnt + i, (float)lh[i]);
}

// ---------------- main segment kernel ----------------
// One wave per src entity: register-accumulate over its CSR edge range, then
// finalize h_ent = ELU(acc / ebs) in-kernel. Only relp uses global atomics.
__global__ __launch_bounds__(256) void k_seg(const int* __restrict__ row_start,
        const int* __restrict__ sdst, const int* __restrict__ srel,
        const float* __restrict__ Ps, const float* __restrict__ Pd, const float* __restrict__ Pr,
        const float* __restrict__ Wa2, const float* __restrict__ ba2,
        float* __restrict__ out, float* __restrict__ relp) {
    const int lane = threadIdx.x & 63;
    const int s = (blockIdx.x * 256 + threadIdx.x) >> 6;   // wave id == entity
    if (s >= N_ENT) return;
    const int copy = blockIdx.x & (NCOPY - 1);
    const float w0 = Wa2[lane], w1 = Wa2[64 + lane];
    const float bb = ba2[0];

    const int beg = row_start[s], end = row_start[s + 1];
    const float ps0 = Ps[(size_t)s * DIM + lane];
    const float ps1 = Ps[(size_t)s * DIM + 64 + lane];

    float acc0 = 0.f, acc1 = 0.f, ebs = 0.f;
    for (int j = beg; j < end; ++j) {
        int d = sdst[j];
        int r = srel[j];
        float c0 = ps0 + Pr[r * DIM + lane]      + Pd[(size_t)d * DIM + lane];
        float c1 = ps1 + Pr[r * DIM + 64 + lane] + Pd[(size_t)d * DIM + 64 + lane];
        float p = c0 * w0 + c1 * w1;
        #pragma unroll
        for (int off = 32; off > 0; off >>= 1) p += __shfl_xor(p, off, 64);
        float b = p + bb;
        b = (b > 0.f) ? b : 0.01f * b;        // leaky_relu slope 0.01
        float eb = expf(b);
        float t0 = eb * c0, t1 = eb * c1;
        acc0 += t0; acc1 += t1; ebs += eb;
        atomicAdd(relp + (size_t)copy * (N_REL * DIM) + r * DIM + lane,      t0);
        atomicAdd(relp + (size_t)copy * (N_REL * DIM) + r * DIM + 64 + lane, t1);
    }

    float ebsv = (ebs == 0.f) ? 1e-12f : ebs;   // matches reference where()
    float h0 = acc0 / ebsv, h1 = acc1 / ebsv;
    out[(size_t)s * DIM + lane]      = (h0 > 0.f) ? h0 : expm1f(h0);  // elu
    out[(size_t)s * DIM + 64 + lane] = (h1 > 0.f) ? h1 : expm1f(h1);
}

__global__ void k_rel_final(float* __restrict__ out, const float* __restrict__ relp,
                            const float* __restrict__ relcnt) {
    int i = blockIdx.x * 256 + threadIdx.x;
    if (i >= N_REL * DIM) return;
    int r = i >> 7;
    float s = 0.f;
    for (int cp = 0; cp < NCOPY; ++cp) s += relp[(size_t)cp * (N_REL * DIM) + i];
    float h = s / fmaxf(relcnt[r], 1.0f);
    out[N_ENT * DIM + i] = (h > 0.f) ? h : expm1f(h);
}

extern "C" void kernel_launch(void* const* d_in, const int* in_sizes, int n_in,
                              void* d_out, int out_size, void* d_ws, size_t ws_size,
                              hipStream_t stream) {
    const int*   trip = (const int*)d_in[0];
    const float* ent  = (const float*)d_in[1];
    const float* rele = (const float*)d_in[2];
    const float* Wa   = (const float*)d_in[3];
    const float* ba   = (const float*)d_in[4];
    const float* Wa2  = (const float*)d_in[5];
    const float* ba2  = (const float*)d_in[6];
    float* out = (float*)d_out;

    float* ws     = (float*)d_ws;
    float* WaT    = ws;                                   // 384*128
    float* Ps     = WaT + 384 * 128;                      // N_ENT*128
    float* Pd     = Ps + (size_t)N_ENT * DIM;             // N_ENT*128
    float* Pr     = Pd + (size_t)N_ENT * DIM;             // N_REL*128
    float* relp   = Pr + N_REL * DIM;                     // NCOPY*N_REL*128
    float* relcnt = relp + (size_t)NCOPY * N_REL * DIM;   // N_REL
    int* row_start = (int*)(relcnt + N_REL);              // N_ENT+1
    int* cursor    = row_start + N_ENT + 1;               // N_ENT (doubles as hist cnt)
    int* bsum      = cursor + N_ENT;                      // 128
    int* sdst      = bsum + 128;                          // NE
    int* srel      = sdst + NE;                           // NE

    hipMemsetAsync(cursor, 0, N_ENT * sizeof(int), stream);
    hipMemsetAsync(relp, 0, ((size_t)NCOPY * N_REL * DIM + N_REL) * sizeof(float), stream);

    k_transpose_wa<<<192, 256, 0, stream>>>(Wa, WaT);
    k_proj_rel<<<(N_REL * DIM + 255) / 256, 256, 0, stream>>>(rele, Wa, ba, Pr);
    k_proj_ent<<<(N_ENT + 63) / 64, 256, 0, stream>>>(ent, WaT, Ps, Pd);

    k_hist<<<(NE + 255) / 256, 256, 0, stream>>>(trip, cursor);
    k_scan1<<<98, 256, 0, stream>>>(cursor, row_start, bsum);
    k_scan2<<<1, 128, 0, stream>>>(bsum);
    k_scan3<<<(N_ENT + 256) / 256, 256, 0, stream>>>(row_start, bsum, cursor);
    k_scatter<<<(NE + 255) / 256, 256, 0, stream>>>(trip, cursor, sdst, srel);
    k_rel_hist<<<(NE + 255) / 256, 256, 0, stream>>>(trip, relcnt);

    k_seg<<<(N_ENT + 3) / 4, 256, 0, stream>>>(row_start, sdst, srel, Ps, Pd, Pr,
                                               Wa2, ba2, out, relp);
    k_rel_final<<<(N_REL * DIM + 255) / 256, 256, 0, stream>>>(out, relp, relcnt);
}